// Round 1
// 97.094 us; speedup vs baseline: 1.0891x; 1.0891x over previous
//
#include <hip/hip_runtime.h>

// Problem: B=2, DIM=512, NUM_HEADS=1, tokens TOK=256 (16x16 window, w=1).
// Pipeline: [qkv GEMM: bf16 split-3 MFMA, Ksplit2] -> [fused per-channel attn, sums 2 parts]
//           -> [proj GEMM: bf16 split-3 MFMA, Ksplit4] -> [combine 4 parts + proj bias]
// fp32 in/out everywhere; GEMMs decompose operands to bf16 hi/lo during LDS
// staging and run 3 MFMAs (Ah*Bh + Al*Bh + Ah*Bl) per k-step, fp32 accum.
// Workspace layout (floats):
//   qkvp  = ws + 0        : 4 parts(ks*2+b) * [1536][256] = 1,572,864
//   aout  = ws + 1572864  : [2][512][256]                 =   262,144
//   projp = ws + 1835008  : 8 parts(ks*2+b) * [512][256]  = 1,048,576
// total 2,883,584 floats = 11.5 MB of d_ws.

#define TOK    256
#define KDIM   512
#define LOG2E  1.4426950408889634f
#define SCALE  0.04419417382415922f   // 512^{-1/2}
#define QPARTS 2                      // qkv K-split parts
#define PPARTS 4                      // proj K-split parts
#define QPSTRIDE 786432               // 2*1536*256, qkv ks-part stride (fixed b)
#define PPSTRIDE 262144               // 2*512*256,  proj ks-part stride

#define EXP2(x) __builtin_amdgcn_exp2f(x)

typedef __attribute__((ext_vector_type(8))) short short8_t;  // 8 bf16 (4 VGPR)
typedef __attribute__((ext_vector_type(4))) float f32x4;     // MFMA acc

// round-to-nearest-even fp32 -> bf16 bits
__device__ __forceinline__ unsigned short f2bf(float x) {
    unsigned int u = __float_as_uint(x);
    u += 0x7fffu + ((u >> 16) & 1u);
    return (unsigned short)(u >> 16);
}
__device__ __forceinline__ float bf2f(unsigned short h) {
    return __uint_as_float((unsigned int)h << 16);
}

// ---------------------------------------------------------------------------
// bf16 split-3 MFMA GEMM, K-split.
// Cpart[z=(ks*2+b)][M][TOK] = A[M x KLEN slice] @ B[b][KLEN slice][TOK]
// Block: 256 thr = 4 waves (2m x 2n). Tile BM x 64, BK=64, full KLEN per block.
// A [M][K] fp32 -> As_h/As_l bf16 [BM][72] (16B-aligned rows, padded).
// B [K][N] fp32 -> Bs packed (hi|lo<<16) words [64n][68k] (transposed in LDS;
//   both store and frag-read are k-contiguous 16B ops -> conflict-free).
// Frags use k-chunk = (lane>>4)*8 + j for BOTH A and B (k-perm invariant).
// C/D: col = lane&15, row = (lane>>4)*4 + reg  (m89-verified mapping).
// ---------------------------------------------------------------------------
template<int BM, int KSPLIT>
__global__ __launch_bounds__(256)
void gemm_mfma(const float* __restrict__ A, const float* __restrict__ Bmat,
               float* __restrict__ C, int M)
{
    constexpr int KLEN = KDIM / KSPLIT;
    constexpr int NT   = KLEN / 64;     // K-tiles per block
    constexpr int MF   = BM / 32;       // 16-row m-frags per wave
    constexpr int AP   = BM / 16;       // float4 A loads per thread per tile
    constexpr int SA   = 72;            // As stride in ushorts (144 B rows)
    constexpr int SB   = 68;            // Bs stride in words   (272 B rows)

    __shared__ unsigned short As_h[BM * SA];
    __shared__ unsigned short As_l[BM * SA];
    __shared__ unsigned int   Bs[64 * SB];

    const int t  = threadIdx.x;
    const int o0 = blockIdx.x * BM;
    const int n0 = blockIdx.y * 64;
    const int z  = blockIdx.z;
    const int b  = z & 1;
    const int ks = z >> 1;

    const float* Ab = A + (size_t)o0 * KDIM + ks * KLEN;
    const float* Bb = Bmat + ((size_t)b * KDIM + (size_t)ks * KLEN) * TOK + n0;
    float*       Cb = C + ((size_t)z * M + o0) * TOK + n0;

    // staging maps
    const int ak4 = (t & 15) * 4;   // A k-quad
    const int am  = t >> 4;         // A row base (step 16 over p)
    const int btt = t & 63;         // B token (n)
    const int bc4 = (t >> 6) * 4;   // B k-quad base (step 16 over p)

    float4 pa[AP];
    float  pb[16];

#define LOAD_TILE(KT) do {                                                    \
        const float* ap_ = Ab + (KT) * 64 + ak4;                              \
        _Pragma("unroll")                                                     \
        for (int p = 0; p < AP; ++p)                                          \
            pa[p] = *(const float4*)(ap_ + (size_t)(am + 16 * p) * KDIM);     \
        const float* bp_ = Bb + (size_t)(KT) * 64 * TOK + btt;                \
        _Pragma("unroll")                                                     \
        for (int p = 0; p < 4; ++p)                                           \
            _Pragma("unroll")                                                 \
            for (int j = 0; j < 4; ++j)                                       \
                pb[p * 4 + j] = bp_[(size_t)(bc4 + p * 16 + j) * TOK];        \
    } while (0)

#define STORE_TILE() do {                                                     \
        _Pragma("unroll")                                                     \
        for (int p = 0; p < AP; ++p) {                                        \
            const int m_ = am + 16 * p;                                       \
            const float4 v_ = pa[p];                                          \
            const unsigned short h0 = f2bf(v_.x), h1 = f2bf(v_.y),            \
                                 h2 = f2bf(v_.z), h3 = f2bf(v_.w);            \
            const unsigned short l0 = f2bf(v_.x - bf2f(h0)),                  \
                                 l1 = f2bf(v_.y - bf2f(h1)),                  \
                                 l2 = f2bf(v_.z - bf2f(h2)),                  \
                                 l3 = f2bf(v_.w - bf2f(h3));                  \
            *(ushort4*)&As_h[(size_t)m_ * SA + ak4] =                         \
                make_ushort4(h0, h1, h2, h3);                                 \
            *(ushort4*)&As_l[(size_t)m_ * SA + ak4] =                         \
                make_ushort4(l0, l1, l2, l3);                                 \
        }                                                                     \
        _Pragma("unroll")                                                     \
        for (int p = 0; p < 4; ++p) {                                         \
            unsigned int wv0, wv1, wv2, wv3;                                  \
            {                                                                 \
                const float x0 = pb[p * 4 + 0], x1 = pb[p * 4 + 1],           \
                            x2 = pb[p * 4 + 2], x3 = pb[p * 4 + 3];           \
                const unsigned short a0 = f2bf(x0), a1 = f2bf(x1),            \
                                     a2 = f2bf(x2), a3 = f2bf(x3);            \
                wv0 = (unsigned int)a0 |                                      \
                      ((unsigned int)f2bf(x0 - bf2f(a0)) << 16);              \
                wv1 = (unsigned int)a1 |                                      \
                      ((unsigned int)f2bf(x1 - bf2f(a1)) << 16);              \
                wv2 = (unsigned int)a2 |                                      \
                      ((unsigned int)f2bf(x2 - bf2f(a2)) << 16);              \
                wv3 = (unsigned int)a3 |                                      \
                      ((unsigned int)f2bf(x3 - bf2f(a3)) << 16);              \
            }                                                                 \
            *(uint4*)&Bs[(size_t)btt * SB + bc4 + p * 16] =                   \
                make_uint4(wv0, wv1, wv2, wv3);                               \
        }                                                                     \
    } while (0)

    // wave decomposition: 2 m-waves x 2 n-waves; wave tile (BM/2) x 32
    const int wid  = t >> 6;
    const int wm   = wid & 1;
    const int wn   = wid >> 1;
    const int lane = t & 63;
    const int lr   = lane & 15;   // frag row (A) / col (B,D)
    const int lg   = lane >> 4;   // k-chunk group / D row-quad

    const int mwb = wm * (BM / 2);
    const int nwb = wn * 32;

    f32x4 acc[MF][2];
#pragma unroll
    for (int mi = 0; mi < MF; ++mi)
#pragma unroll
        for (int ni = 0; ni < 2; ++ni)
            acc[mi][ni] = (f32x4){0.f, 0.f, 0.f, 0.f};

    LOAD_TILE(0);
    STORE_TILE();
    __syncthreads();

#pragma unroll
    for (int kt = 0; kt < NT; ++kt) {
        if (kt + 1 < NT) LOAD_TILE(kt + 1);   // prefetch next tile to regs

#pragma unroll
        for (int ksp = 0; ksp < 2; ++ksp) {   // two K=32 steps per tile
            const int kb = ksp * 32 + lg * 8; // elem (ushort/word) offset

            short8_t ah[MF], al[MF];
#pragma unroll
            for (int mi = 0; mi < MF; ++mi) {
                const int m_ = mwb + mi * 16 + lr;
                ah[mi] = *(const short8_t*)&As_h[(size_t)m_ * SA + kb];
                al[mi] = *(const short8_t*)&As_l[(size_t)m_ * SA + kb];
            }

            short8_t bh[2], bl[2];
#pragma unroll
            for (int ni = 0; ni < 2; ++ni) {
                const unsigned int* wp =
                    &Bs[(size_t)(nwb + ni * 16 + lr) * SB + kb];
                const uint4 w0 = *(const uint4*)wp;
                const uint4 w1 = *(const uint4*)(wp + 4);
                short8_t h_, l_;
                h_[0] = (short)(w0.x & 0xffffu); l_[0] = (short)(w0.x >> 16);
                h_[1] = (short)(w0.y & 0xffffu); l_[1] = (short)(w0.y >> 16);
                h_[2] = (short)(w0.z & 0xffffu); l_[2] = (short)(w0.z >> 16);
                h_[3] = (short)(w0.w & 0xffffu); l_[3] = (short)(w0.w >> 16);
                h_[4] = (short)(w1.x & 0xffffu); l_[4] = (short)(w1.x >> 16);
                h_[5] = (short)(w1.y & 0xffffu); l_[5] = (short)(w1.y >> 16);
                h_[6] = (short)(w1.z & 0xffffu); l_[6] = (short)(w1.z >> 16);
                h_[7] = (short)(w1.w & 0xffffu); l_[7] = (short)(w1.w >> 16);
                bh[ni] = h_; bl[ni] = l_;
            }

#pragma unroll
            for (int mi = 0; mi < MF; ++mi)
#pragma unroll
                for (int ni = 0; ni < 2; ++ni) {
                    acc[mi][ni] = __builtin_amdgcn_mfma_f32_16x16x32_bf16(
                        ah[mi], bh[ni], acc[mi][ni], 0, 0, 0);
                    acc[mi][ni] = __builtin_amdgcn_mfma_f32_16x16x32_bf16(
                        al[mi], bh[ni], acc[mi][ni], 0, 0, 0);
                    acc[mi][ni] = __builtin_amdgcn_mfma_f32_16x16x32_bf16(
                        ah[mi], bl[ni], acc[mi][ni], 0, 0, 0);
                }
        }

        if (kt + 1 < NT) {
            __syncthreads();
            STORE_TILE();
            __syncthreads();
        }
    }

    // epilogue: D frag -> global (lanes 0..15 of each quad write one row)
#pragma unroll
    for (int mi = 0; mi < MF; ++mi)
#pragma unroll
        for (int ni = 0; ni < 2; ++ni)
#pragma unroll
            for (int r = 0; r < 4; ++r) {
                const int row = mwb + mi * 16 + lg * 4 + r;
                const int col = nwb + ni * 16 + lr;
                Cb[(size_t)row * TOK + col] = acc[mi][ni][r];
            }
#undef LOAD_TILE
#undef STORE_TILE
}

// ---------------------------------------------------------------------------
// Fused per-channel attention (sums the 2 qkv K-split parts inline).
// Block = 256 threads handles (b, d0..d0+1): waves = (dl, g-half).
// bias[h,g] = tab[r(h)-r(g)+30], r(h)=(h>>4)+(h&15): 61 distinct values,
// replicated into brow[31][258] (2-bank step, conflict-free float2 reads).
// Scores bounded (~1.1) -> no max-subtraction; g-half partials merge additively.
// ---------------------------------------------------------------------------
__global__ __launch_bounds__(256)
void attn_f32(const float* __restrict__ qkvp, const float* __restrict__ qkv_b,
              const float* __restrict__ rpb, float* __restrict__ aout)
{
    __shared__ float ks_[2][TOK];      // k * scale * log2e (incl. qkv bias)
    __shared__ float vs_[2][TOK];      // v (incl. qkv bias)
    __shared__ float tab2[64];         // rpb gathered, * log2e
    __shared__ float brow[31][258];    // bias rows, stride 258 (2-bank step)
    __shared__ float lpart[2][TOK];
    __shared__ float apart[2][TOK];

    const int t  = threadIdx.x;
    const int b  = blockIdx.y;
    const int d0 = blockIdx.x * 2;
    const float* q0 = qkvp + (size_t)b * (1536 * TOK);

    // phase 0: bias table (61 values)
    if (t < 61) {
        const int rel = t - 30;
        tab2[t] = rpb[rel < 0 ? rel + 961 : rel] * LOG2E;
    }
    // phase 1: stage k and v for the 2 channels (sum 2 K-split parts + bias)
    {
        const int sel = t >> 7;          // 0: k, 1: v
        const int row = (t >> 6) & 1;    // dl
        const int g4  = (t & 63) * 4;
        const int o   = (sel ? 1024 : 512) + d0 + row;
        const float* p = q0 + (size_t)o * TOK + g4;
        const float bb = qkv_b[o];
        float4 v = make_float4(bb, bb, bb, bb);
#pragma unroll
        for (int pp = 0; pp < QPARTS; ++pp) {
            const float4 x = *(const float4*)(p + (size_t)pp * QPSTRIDE);
            v.x += x.x; v.y += x.y; v.z += x.z; v.w += x.w;
        }
        if (sel == 0) {
            const float s = SCALE * LOG2E;
            v.x *= s; v.y *= s; v.z *= s; v.w *= s;
            *(float4*)&ks_[row][g4] = v;
        } else {
            *(float4*)&vs_[row][g4] = v;
        }
    }
    __syncthreads();
    // phase 2: replicate bias into 31 rows x 256 g
    {
        const int rg = ((t >> 4) & 15) + (t & 15);
#pragma unroll 1
        for (int it = 0; it < 31; ++it)
            brow[it][t] = tab2[it - rg + 30];
    }
    __syncthreads();

    // phase 3: main loop
    const int w   = t >> 6;
    const int dl  = w & 1;
    const int gh  = w >> 1;
    const int hl  = t & 63;
    const int qi  = ((hl & 15) << 2) | (hl >> 4);  // bit-swizzled h-quad index
    const int h0  = qi * 4;
    const int rh0 = (qi >> 2) + 4 * (qi & 3);      // r(h0); r(h0+r)=rh0+r

    float q[4];
    {
        const float* p = q0 + (size_t)(d0 + dl) * TOK + h0;
        const float bb = qkv_b[d0 + dl];
        q[0] = bb; q[1] = bb; q[2] = bb; q[3] = bb;
#pragma unroll
        for (int pp = 0; pp < QPARTS; ++pp) {
            const float4 x = *(const float4*)(p + (size_t)pp * QPSTRIDE);
            q[0] += x.x; q[1] += x.y; q[2] += x.z; q[3] += x.w;
        }
    }

    float l[4]  = {0.f, 0.f, 0.f, 0.f};
    float am[4] = {0.f, 0.f, 0.f, 0.f};

    const int pbeg = gh * 128;
#pragma unroll 2
    for (int p = pbeg; p < pbeg + 128; p += 4) {
        const float4 k4 = *(const float4*)&ks_[dl][p];   // wave-uniform (bcast)
        const float4 v4 = *(const float4*)&vs_[dl][p];
#pragma unroll
        for (int r = 0; r < 4; ++r) {
            const float2 b01 = *(const float2*)&brow[rh0 + r][p];
            const float2 b23 = *(const float2*)&brow[rh0 + r][p + 2];
            float e;
            e = EXP2(fmaf(q[r], k4.x, b01.x)); l[r] += e; am[r] = fmaf(e, v4.x, am[r]);
            e = EXP2(fmaf(q[r], k4.y, b01.y)); l[r] += e; am[r] = fmaf(e, v4.y, am[r]);
            e = EXP2(fmaf(q[r], k4.z, b23.x)); l[r] += e; am[r] = fmaf(e, v4.z, am[r]);
            e = EXP2(fmaf(q[r], k4.w, b23.y)); l[r] += e; am[r] = fmaf(e, v4.w, am[r]);
        }
    }

    // phase 4: merge g-halves, normalize, store
    if (gh == 1) {
        *(float4*)&lpart[dl][h0] = make_float4(l[0], l[1], l[2], l[3]);
        *(float4*)&apart[dl][h0] = make_float4(am[0], am[1], am[2], am[3]);
    }
    __syncthreads();
    if (gh == 0) {
        const float4 lo = *(const float4*)&lpart[dl][h0];
        const float4 ao = *(const float4*)&apart[dl][h0];
        float4 o4;
        o4.x = (am[0] + ao.x) / (l[0] + lo.x);
        o4.y = (am[1] + ao.y) / (l[1] + lo.y);
        o4.z = (am[2] + ao.z) / (l[2] + lo.z);
        o4.w = (am[3] + ao.w) / (l[3] + lo.w);
        *(float4*)(aout + ((size_t)b * 512 + d0 + dl) * TOK + h0) = o4;
    }
}

// ---------------------------------------------------------------------------
// Sum the 4 proj K-split parts + proj bias -> final output [2][512][256]
// ---------------------------------------------------------------------------
__global__ __launch_bounds__(256)
void combine_f32(const float* __restrict__ pp, const float* __restrict__ pb,
                 float* __restrict__ out)
{
    const int gid  = blockIdx.x * 256 + threadIdx.x;
    const int flat = gid * 4;
    const int o = (flat >> 8) & 511;
    float4 a = make_float4(pb[o], pb[o], pb[o], pb[o]);
#pragma unroll
    for (int p = 0; p < PPARTS; ++p) {
        const float4 x = *(const float4*)(pp + (size_t)p * PPSTRIDE + flat);
        a.x += x.x; a.y += x.y; a.z += x.z; a.w += x.w;
    }
    *(float4*)(out + flat) = a;
}

// ---------------------------------------------------------------------------
extern "C" void kernel_launch(void* const* d_in, const int* in_sizes, int n_in,
                              void* d_out, int out_size, void* d_ws, size_t ws_size,
                              hipStream_t stream)
{
    const float* x      = (const float*)d_in[0];   // [2][512][256]
    const float* qkv_w  = (const float*)d_in[1];   // [1536][512]
    const float* qkv_b  = (const float*)d_in[2];   // [1536]
    const float* proj_w = (const float*)d_in[3];   // [512][512]
    const float* proj_b = (const float*)d_in[4];   // [512]
    const float* rpb    = (const float*)d_in[5];   // [961]
    float* out = (float*)d_out;                    // [2][512][256]
    float* ws  = (float*)d_ws;

    float* qkvp  = ws;                 // 4 * 393216
    float* aout  = ws + 1572864;       // 262144
    float* projp = ws + 1835008;       // 8 * 131072

    // qkv = qkv_w @ x: M=1536, BM=128, Ksplit=2 -> grid (12, 4, 4) = 192 blocks
    gemm_mfma<128, 2><<<dim3(12, 4, 4), 256, 0, stream>>>(qkv_w, x, qkvp, 1536);

    // fused attention: grid (d-pairs=256, b=2), sums 2 qkv parts inline
    attn_f32<<<dim3(256, 2), 256, 0, stream>>>(qkvp, qkv_b, rpb, aout);

    // proj = proj_w @ aout: M=512, BM=64, Ksplit=4 -> grid (8, 4, 8) = 256 blocks
    gemm_mfma<64, 4><<<dim3(8, 4, 8), 256, 0, stream>>>(proj_w, aout, projp, 512);

    // sum 4 parts + bias
    combine_f32<<<dim3(256), 256, 0, stream>>>(projp, proj_b, out);
}